// Round 5
// baseline (711.169 us; speedup 1.0000x reference)
//
#include <hip/hip_runtime.h>

// B=8, C=384, 96x96 stride-2 -> 48x48, N=2304 tokens.
// qkv = W(1152x384) @ xs(384xN); 6 heads x (q,k,v) of 64 dims.
// attn = softmax(q^T k); out[d][n] = sum_m v[d][m] P[n][m].
// All matmuls on MFMA via 3-term bf16 split (hi*hi + hi*lo + lo*hi).
// Q rows of W pre-scaled by log2(e); softmax runs in the exp2 domain.

#define NTOK 2304
#define NB 8
#define W_U16 (1152 * 384)             // one W bf16 plane
#define XT_U16 (NTOK * 384)            // one xsT bf16 plane
#define PLANE_U16 (NTOK * 64)          // one qkv bf16 plane
#define HEAD_U16 (5 * PLANE_U16)       // qhi,qlo + kv-tiles(3 planes worth)
#define SLOT_U16 (2 * XT_U16 + 6 * HEAD_U16)
#define SLOT_BYTES ((size_t)SLOT_U16 * 2)     // 12.39 MB / batch
#define WBYTES ((size_t)W_U16 * 2 * 2)        // 1.77 MB
#define LOG2E 1.4426950408889634f

typedef __attribute__((ext_vector_type(8))) short bf16x8;
typedef __attribute__((ext_vector_type(4))) float f32x4;

__device__ __forceinline__ ushort f2bf(float f) {
  union { float f; uint u; } v; v.f = f;
  uint u = v.u;
  return (ushort)((u + 0x7fffu + ((u >> 16) & 1u)) >> 16);  // RNE
}
__device__ __forceinline__ float bf2f(ushort h) {
  union { uint u; float f; } v; v.u = ((uint)h) << 16; return v.f;
}
__device__ __forceinline__ uint cvt_pk_bf16(float lo, float hi) {
  uint r;
  asm("v_cvt_pk_bf16_f32 %0, %1, %2" : "=v"(r) : "v"(lo), "v"(hi));
  return r;
}
__device__ __forceinline__ float exp2_fast(float x) {
  float r;
  asm("v_exp_f32 %0, %1" : "=v"(r) : "v"(x));
  return r;
}
__device__ __forceinline__ float max3f(float a, float b, float c) {
  float r;
  asm("v_max3_f32 %0, %1, %2, %3" : "=v"(r) : "v"(a), "v"(b), "v"(c));
  return r;
}

// ---------------------------------------------------------------------------
// Kernel W: split W into hi/lo bf16 planes; q-rows pre-scaled by log2(e).
// ---------------------------------------------------------------------------
__global__ __launch_bounds__(256) void prep_w_kernel(
    const float* __restrict__ w, ushort* __restrict__ wsu) {
  const int idx4 = blockIdx.x * 256 + threadIdx.x;  // 110592 total
  const int o = idx4 / 96;                          // W row (384 cols / 4)
  const float scale = ((o % 192) < 64) ? LOG2E : 1.0f;
  float4 v = *(const float4*)&w[(size_t)idx4 * 4];
  float f[4] = {v.x * scale, v.y * scale, v.z * scale, v.w * scale};
  ushort hi[4], lo[4];
#pragma unroll
  for (int j = 0; j < 4; ++j) {
    hi[j] = f2bf(f[j]);
    lo[j] = f2bf(f[j] - bf2f(hi[j]));
  }
  uint2 uh, ul;
  uh.x = (uint)hi[0] | ((uint)hi[1] << 16); uh.y = (uint)hi[2] | ((uint)hi[3] << 16);
  ul.x = (uint)lo[0] | ((uint)lo[1] << 16); ul.y = (uint)lo[2] | ((uint)lo[3] << 16);
  *(uint2*)&wsu[(size_t)idx4 * 4] = uh;
  *(uint2*)&wsu[W_U16 + (size_t)idx4 * 4] = ul;
}

// ---------------------------------------------------------------------------
// Kernel X: subsample + transpose + split x -> xsT[n][c] hi/lo bf16.
// ---------------------------------------------------------------------------
__global__ __launch_bounds__(256) void prep_x_kernel(
    const float* __restrict__ x, ushort* __restrict__ wsu, int b0) {
  const int hh = blockIdx.x, cc = blockIdx.y, bb = blockIdx.z;
  const int b = b0 + bb;
  const int c0 = cc * 64;
  ushort* slot = wsu + 2 * (size_t)W_U16 + (size_t)bb * SLOT_U16;
  ushort* xthi = slot;
  ushort* xtlo = slot + XT_U16;
  const float* xb = x + ((size_t)b * 384 + c0) * 9216 + 192 * hh;

  __shared__ float T[64][49];
  const int tid = threadIdx.x;
#pragma unroll
  for (int i = 0; i < 8; ++i) {
    int idx = tid + 256 * i;
    int cl = idx >> 5, q = idx & 31;
    if (q < 24) {
      float4 v = *(const float4*)&xb[(size_t)cl * 9216 + 4 * q];
      T[cl][2 * q] = v.x;
      T[cl][2 * q + 1] = v.z;
    }
  }
  __syncthreads();
#pragma unroll
  for (int i = 0; i < 2; ++i) {
    int item = tid + 256 * i;
    if (item < 384) {
      int ww = item >> 3, cg = item & 7;
      int n = hh * 48 + ww;
      uint uh[4], ul[4];
#pragma unroll
      for (int p = 0; p < 4; ++p) {
        float f0 = T[8 * cg + 2 * p][ww], f1 = T[8 * cg + 2 * p + 1][ww];
        ushort h0 = f2bf(f0), h1 = f2bf(f1);
        ushort l0 = f2bf(f0 - bf2f(h0)), l1 = f2bf(f1 - bf2f(h1));
        uh[p] = (uint)h0 | ((uint)h1 << 16);
        ul[p] = (uint)l0 | ((uint)l1 << 16);
      }
      uint4 H = {uh[0], uh[1], uh[2], uh[3]};
      uint4 L = {ul[0], ul[1], ul[2], ul[3]};
      *(uint4*)&xthi[(size_t)n * 384 + c0 + 8 * cg] = H;
      *(uint4*)&xtlo[(size_t)n * 384 + c0 + 8 * cg] = L;
    }
  }
}

// ---------------------------------------------------------------------------
// Kernel G: MFMA projection GEMM with reg-staged prefetch across K-steps.
// Epilogue writes attention-ready layouts:
//  t=0 (q): [n][64] hi/lo (already log2e-scaled via W)
//  t=1 (k): per-64-key swizzled tile, planes hi/lo (tile = 24 KB: Khi|Klo|V)
//  t=2 (v): same tile, plane 2, rows = d, cols = key, row-swizzled
// ---------------------------------------------------------------------------
__global__ __launch_bounds__(256) void qkv_mfma_kernel(
    const ushort* __restrict__ wsu, int b0) {
  const int nT = blockIdx.x, oT = blockIdx.y, bb = blockIdx.z;
  const ushort* whi = wsu;
  const ushort* wlo = wsu + W_U16;
  const ushort* slot = wsu + 2 * (size_t)W_U16 + (size_t)bb * SLOT_U16;
  const ushort* xthi = slot;
  const ushort* xtlo = slot + XT_U16;
  const int oBase = oT * 64, nBase = nT * 64;

  __shared__ __align__(16) ushort Wh[64 * 64];
  __shared__ __align__(16) ushort Wl[64 * 64];
  __shared__ __align__(16) ushort Xh[64 * 64];
  __shared__ __align__(16) ushort Xl[64 * 64];

  const int tid = threadIdx.x;
  const int w = tid >> 6, l = tid & 63;
  const int lq = l & 15, lh = l >> 4;

  f32x4 acc[4];
#pragma unroll
  for (int f = 0; f < 4; ++f) acc[f] = (f32x4){0.f, 0.f, 0.f, 0.f};

  uint4 stg[8];
  auto stage = [&](int c0) {
#pragma unroll
    for (int i = 0; i < 8; ++i) {
      int f = tid + 256 * i;
      int plane = f >> 9;
      int idx = f & 511;
      int row = idx >> 3, g = idx & 7;
      const ushort* sp;
      if (plane == 0)      sp = whi + (size_t)(oBase + row) * 384 + c0 + 8 * g;
      else if (plane == 1) sp = wlo + (size_t)(oBase + row) * 384 + c0 + 8 * g;
      else if (plane == 2) sp = xthi + (size_t)(nBase + row) * 384 + c0 + 8 * g;
      else                 sp = xtlo + (size_t)(nBase + row) * 384 + c0 + 8 * g;
      stg[i] = *(const uint4*)sp;
    }
  };
  auto commit = [&]() {
#pragma unroll
    for (int i = 0; i < 8; ++i) {
      int f = tid + 256 * i;
      int plane = f >> 9;
      int idx = f & 511;
      int row = idx >> 3, g = idx & 7;
      ushort* dp = (plane == 0) ? Wh : (plane == 1) ? Wl : (plane == 2) ? Xh : Xl;
      *(uint4*)&dp[row * 64 + 8 * (g ^ (row & 7))] = stg[i];
    }
  };

  stage(0);
  for (int step = 0; step < 6; ++step) {
    commit();            // vmcnt wait inserted here by compiler
    __syncthreads();     // LDS tile ready
    if (step < 5) stage((step + 1) * 64);  // in flight during compute
    __builtin_amdgcn_s_setprio(1);
#pragma unroll
    for (int s = 0; s < 2; ++s) {
      const int nrow = 16 * w + lq;
      const int g = 4 * s + lh;
      const int noff = nrow * 64 + 8 * (g ^ (nrow & 7));
      bf16x8 xh = *(const bf16x8*)&Xh[noff];
      bf16x8 xl = *(const bf16x8*)&Xl[noff];
#pragma unroll
      for (int f = 0; f < 4; ++f) {
        const int orow = 16 * f + lq;
        const int ooff = orow * 64 + 8 * (g ^ (orow & 7));
        bf16x8 wh_ = *(const bf16x8*)&Wh[ooff];
        bf16x8 wl_ = *(const bf16x8*)&Wl[ooff];
        acc[f] = __builtin_amdgcn_mfma_f32_16x16x32_bf16(wh_, xh, acc[f], 0, 0, 0);
        acc[f] = __builtin_amdgcn_mfma_f32_16x16x32_bf16(wh_, xl, acc[f], 0, 0, 0);
        acc[f] = __builtin_amdgcn_mfma_f32_16x16x32_bf16(wl_, xh, acc[f], 0, 0, 0);
      }
    }
    __builtin_amdgcn_s_setprio(0);
    __syncthreads();     // all waves done reading before next commit
  }

  const int t = oT % 3, head = oT / 3;
  ushort* pb = (ushort*)slot + 2 * (size_t)XT_U16 + (size_t)head * HEAD_U16;
  if (t == 0) {  // q: [n][64] hi/lo (log2e already folded into W)
    ushort* phi = pb;
    ushort* plo = pb + PLANE_U16;
    const int n = nBase + 16 * w + lq;
#pragma unroll
    for (int f = 0; f < 4; ++f) {
      ushort hi[4], lo[4];
#pragma unroll
      for (int r = 0; r < 4; ++r) {
        hi[r] = f2bf(acc[f][r]);
        lo[r] = f2bf(acc[f][r] - bf2f(hi[r]));
      }
      uint2 uh, ul;
      uh.x = (uint)hi[0] | ((uint)hi[1] << 16); uh.y = (uint)hi[2] | ((uint)hi[3] << 16);
      ul.x = (uint)lo[0] | ((uint)lo[1] << 16); ul.y = (uint)lo[2] | ((uint)lo[3] << 16);
      const int d = 16 * f + 4 * lh;
      *(uint2*)&phi[(size_t)n * 64 + d] = uh;
      *(uint2*)&plo[(size_t)n * 64 + d] = ul;
    }
  } else if (t == 1) {  // k: swizzled tile planes 0 (hi) and 1 (lo)
    ushort* kv = pb + 2 * (size_t)PLANE_U16 + (size_t)nT * 12288;
    const int row = 16 * w + lq;  // key within tile
#pragma unroll
    for (int f = 0; f < 4; ++f) {
      ushort hi[4], lo[4];
#pragma unroll
      for (int r = 0; r < 4; ++r) {
        hi[r] = f2bf(acc[f][r]);
        lo[r] = f2bf(acc[f][r] - bf2f(hi[r]));
      }
      uint2 uh, ul;
      uh.x = (uint)hi[0] | ((uint)hi[1] << 16); uh.y = (uint)hi[2] | ((uint)hi[3] << 16);
      ul.x = (uint)lo[0] | ((uint)lo[1] << 16); ul.y = (uint)lo[2] | ((uint)lo[3] << 16);
      const int idx = row * 64 + 8 * ((2 * f + (lh >> 1)) ^ (row & 7)) + 4 * (lh & 1);
      *(uint2*)&kv[idx] = uh;
      *(uint2*)&kv[4096 + idx] = ul;
    }
  } else {  // v: swizzled tile plane 2, rows = d
    ushort* pv = pb + 2 * (size_t)PLANE_U16 + (size_t)nT * 12288 + 8192;
    const int col = 16 * w + lq;  // key within tile
    const int cg = col >> 3, cr = col & 7;
#pragma unroll
    for (int f = 0; f < 4; ++f)
#pragma unroll
      for (int r = 0; r < 4; ++r) {
        const int row = 16 * f + 4 * lh + r;
        pv[row * 64 + 8 * (cg ^ (row & 7)) + cr] = f2bf(acc[f][r]);
      }
  }
}

// ---------------------------------------------------------------------------
// Kernel B: MFMA flash attention.  Reg-staged prefetch of pre-swizzled 24 KB
// KV tiles (loads for tile t+1 in flight during compute of tile t);
// exp2-domain softmax with defer-max; cvt_pk P packing; setprio on MFMA.
// ---------------------------------------------------------------------------
__global__ __launch_bounds__(256, 4) void attn_mfma_kernel(
    const ushort* __restrict__ wsu, float* __restrict__ out, int b0) {
  const int qt = blockIdx.x, h = blockIdx.y, bb = blockIdx.z;
  const int b = b0 + bb;
  const ushort* pb = wsu + 2 * (size_t)W_U16 + (size_t)bb * SLOT_U16 +
                     2 * (size_t)XT_U16 + (size_t)h * HEAD_U16;
  const ushort* qhiP = pb;
  const ushort* qloP = pb + PLANE_U16;
  const char* kvG = (const char*)(pb + 2 * (size_t)PLANE_U16);  // 36 x 24576 B
  const int n0 = qt * 64;

  __shared__ __align__(16) ushort KV[12288];   // Khi | Klo | Vh (pre-swizzled)
  __shared__ __align__(16) ushort Pw[4][16 * 64];

  const int tid = threadIdx.x;
  const int w = tid >> 6;
  const int l = tid & 63;
  const int lq = l & 15;
  const int lh = l >> 4;

  bf16x8 qh[2], ql[2];
  {
    const int qrow = n0 + 16 * w + lq;
    const ushort* qr = qhiP + (size_t)qrow * 64 + 8 * lh;
    const ushort* qr2 = qloP + (size_t)qrow * 64 + 8 * lh;
    qh[0] = *(const bf16x8*)(qr);
    qh[1] = *(const bf16x8*)(qr + 32);
    ql[0] = *(const bf16x8*)(qr2);
    ql[1] = *(const bf16x8*)(qr2 + 32);
  }

  f32x4 oac[4];
#pragma unroll
  for (int i = 0; i < 4; ++i) oac[i] = (f32x4){0.f, 0.f, 0.f, 0.f};
  float m_run = -3.0e38f, l_run = 0.f;

  const char* gbase = kvG + w * 6144 + l * 16;
  char* lbase = (char*)&KV[0] + w * 6144 + l * 16;

  uint4 stg[6];
  auto stage = [&](int mt) {
    const char* p = gbase + (size_t)mt * 24576;
#pragma unroll
    for (int i = 0; i < 6; ++i) stg[i] = *(const uint4*)(p + i * 1024);
  };
  auto commit = [&]() {
#pragma unroll
    for (int i = 0; i < 6; ++i) *(uint4*)(lbase + i * 1024) = stg[i];
  };

  stage(0);
  commit();
  __syncthreads();

  for (int mt = 0; mt < 36; ++mt) {
    const bool hasNext = (mt + 1 < 36);
    if (hasNext) stage(mt + 1);  // global loads in flight during compute

    const ushort* Khi = &KV[0];
    const ushort* Klo = &KV[4096];
    const ushort* Vh = &KV[8192];

    f32x4 st[4];
#pragma unroll
    for (int f = 0; f < 4; ++f) st[f] = (f32x4){0.f, 0.f, 0.f, 0.f};
    __builtin_amdgcn_s_setprio(1);
#pragma unroll
    for (int f = 0; f < 4; ++f) {
#pragma unroll
      for (int s = 0; s < 2; ++s) {
        const int row = 16 * f + lq;
        const int g = 4 * s + lh;
        const int off = row * 64 + 8 * (g ^ (row & 7));
        bf16x8 ah = *(const bf16x8*)&Khi[off];
        bf16x8 al = *(const bf16x8*)&Klo[off];
        st[f] = __builtin_amdgcn_mfma_f32_16x16x32_bf16(ah, qh[s], st[f], 0, 0, 0);
        st[f] = __builtin_amdgcn_mfma_f32_16x16x32_bf16(ah, ql[s], st[f], 0, 0, 0);
        st[f] = __builtin_amdgcn_mfma_f32_16x16x32_bf16(al, qh[s], st[f], 0, 0, 0);
      }
    }
    __builtin_amdgcn_s_setprio(0);

    // Row max across this tile (partners at lane^16, lane^32).
    float tm = max3f(st[0][0], st[0][1], st[0][2]);
    tm = max3f(tm, st[0][3], st[1][0]);
    tm = max3f(tm, st[1][1], st[1][2]);
    tm = max3f(tm, st[1][3], st[2][0]);
    tm = max3f(tm, st[2][1], st[2][2]);
    tm = max3f(tm, st[2][3], st[3][0]);
    tm = max3f(tm, st[3][1], st[3][2]);
    tm = fmaxf(tm, st[3][3]);
    tm = fmaxf(tm, __shfl_xor(tm, 16));
    tm = fmaxf(tm, __shfl_xor(tm, 32));

    // Defer-max: only rescale when the running max grew by > 8 (exp2 domain).
    if (__any(tm > m_run + 8.0f)) {
      const float mnew = fmaxf(m_run, tm);
      const float sc = exp2_fast(m_run - mnew);
#pragma unroll
      for (int fd = 0; fd < 4; ++fd) oac[fd] *= sc;
      l_run *= sc;
      m_run = mnew;
    }

    float ls = 0.f;
#pragma unroll
    for (int f = 0; f < 4; ++f)
#pragma unroll
      for (int r = 0; r < 4; ++r) {
        st[f][r] = exp2_fast(st[f][r] - m_run);
        ls += st[f][r];
      }
    ls += __shfl_xor(ls, 16);
    ls += __shfl_xor(ls, 32);
    l_run += ls;

    // Pack P to bf16 and bounce through per-wave swizzled LDS.
    ushort* pw = &Pw[w][0];
#pragma unroll
    for (int f = 0; f < 4; ++f) {
      uint2 uu;
      uu.x = cvt_pk_bf16(st[f][0], st[f][1]);
      uu.y = cvt_pk_bf16(st[f][2], st[f][3]);
      int ui = lq * 64 + 8 * ((2 * f + (lh >> 1)) ^ (lq & 7)) + 4 * (lh & 1);
      *(uint2*)&pw[ui] = uu;
    }
    bf16x8 pbf[2];
#pragma unroll
    for (int s = 0; s < 2; ++s)
      pbf[s] = *(const bf16x8*)&pw[lq * 64 + 8 * ((4 * s + lh) ^ (lq & 7))];

    __builtin_amdgcn_s_setprio(1);
#pragma unroll
    for (int fd = 0; fd < 4; ++fd) {
#pragma unroll
      for (int s = 0; s < 2; ++s) {
        const int row = 16 * fd + lq;
        const int g = 4 * s + lh;
        bf16x8 av = *(const bf16x8*)&Vh[row * 64 + 8 * (g ^ (row & 7))];
        oac[fd] = __builtin_amdgcn_mfma_f32_16x16x32_bf16(av, pbf[s], oac[fd], 0, 0, 0);
      }
    }
    __builtin_amdgcn_s_setprio(0);

    if (hasNext) {
      __syncthreads();   // all waves done reading KV
      commit();          // vmcnt wait here is free (loads had whole compute)
      __syncthreads();   // next tile ready
    }
  }

  const float inv = 1.f / l_run;
  const int ncol = n0 + 16 * w + lq;
#pragma unroll
  for (int fd = 0; fd < 4; ++fd)
#pragma unroll
    for (int r = 0; r < 4; ++r)
      out[((size_t)b * 384 + h * 64 + 16 * fd + 4 * lh + r) * NTOK + ncol] =
          oac[fd][r] * inv;
}

extern "C" void kernel_launch(void* const* d_in, const int* in_sizes, int n_in,
                              void* d_out, int out_size, void* d_ws,
                              size_t ws_size, hipStream_t stream) {
  const float* x = (const float*)d_in[0];
  const float* w = (const float*)d_in[1];
  float* out = (float*)d_out;
  ushort* wsu = (ushort*)d_ws;

  int nbFit = (int)((ws_size - WBYTES) / SLOT_BYTES);
  if (nbFit < 1) nbFit = 1;
  if (nbFit > NB) nbFit = NB;

  hipLaunchKernelGGL(prep_w_kernel, dim3(432), dim3(256), 0, stream, w, wsu);
  for (int b0 = 0; b0 < NB; b0 += nbFit) {
    int nb = NB - b0;
    if (nb > nbFit) nb = nbFit;
    hipLaunchKernelGGL(prep_x_kernel, dim3(48, 6, nb), dim3(256), 0, stream,
                       x, wsu, b0);
    hipLaunchKernelGGL(qkv_mfma_kernel, dim3(36, 18, nb), dim3(256), 0, stream,
                       wsu, b0);
    hipLaunchKernelGGL(attn_mfma_kernel, dim3(36, 6, nb), dim3(256), 0, stream,
                       wsu, out, b0);
  }
}

// Round 6
// 240.576 us; speedup vs baseline: 2.9561x; 2.9561x over previous
//
#include <hip/hip_runtime.h>

// B=8, C=384, 96x96 stride-2 -> 48x48, N=2304 tokens.
// qkv = W(1152x384) @ xs(384xN); 6 heads x (q,k,v) of 64 dims.
// attn = softmax(q^T k); out[d][n] = sum_m v[d][m] P[n][m].
// All matmuls on MFMA via 3-term bf16 split (hi*hi + hi*lo + lo*hi).
// Q rows of W pre-scaled by log2(e); softmax runs in the exp2 domain.

#define NTOK 2304
#define NB 8
#define W_U16 (1152 * 384)             // one W bf16 plane
#define XT_U16 (NTOK * 384)            // one xsT bf16 plane
#define PLANE_U16 (NTOK * 64)          // one qkv bf16 plane
#define HEAD_U16 (5 * PLANE_U16)       // qhi,qlo + kv-tiles(3 planes worth)
#define SLOT_U16 (2 * XT_U16 + 6 * HEAD_U16)
#define SLOT_BYTES ((size_t)SLOT_U16 * 2)     // 12.39 MB / batch
#define WBYTES ((size_t)W_U16 * 2 * 2)        // 1.77 MB
#define LOG2E 1.4426950408889634f

typedef __attribute__((ext_vector_type(8))) short bf16x8;
typedef __attribute__((ext_vector_type(4))) float f32x4;

__device__ __forceinline__ ushort f2bf(float f) {
  union { float f; uint u; } v; v.f = f;
  uint u = v.u;
  return (ushort)((u + 0x7fffu + ((u >> 16) & 1u)) >> 16);  // RNE
}
__device__ __forceinline__ float bf2f(ushort h) {
  union { uint u; float f; } v; v.u = ((uint)h) << 16; return v.f;
}
__device__ __forceinline__ uint cvt_pk_bf16(float lo, float hi) {
  uint r;
  asm("v_cvt_pk_bf16_f32 %0, %1, %2" : "=v"(r) : "v"(lo), "v"(hi));
  return r;
}
__device__ __forceinline__ float exp2_fast(float x) {
  float r;
  asm("v_exp_f32 %0, %1" : "=v"(r) : "v"(x));
  return r;
}
__device__ __forceinline__ float max3f(float a, float b, float c) {
  float r;
  asm("v_max3_f32 %0, %1, %2, %3" : "=v"(r) : "v"(a), "v"(b), "v"(c));
  return r;
}

// ---------------------------------------------------------------------------
// Kernel W: split W into hi/lo bf16 planes; q-rows pre-scaled by log2(e).
// ---------------------------------------------------------------------------
__global__ __launch_bounds__(256) void prep_w_kernel(
    const float* __restrict__ w, ushort* __restrict__ wsu) {
  const int idx4 = blockIdx.x * 256 + threadIdx.x;  // 110592 total
  const int o = idx4 / 96;                          // W row (384 cols / 4)
  const float scale = ((o % 192) < 64) ? LOG2E : 1.0f;
  float4 v = *(const float4*)&w[(size_t)idx4 * 4];
  float f[4] = {v.x * scale, v.y * scale, v.z * scale, v.w * scale};
  ushort hi[4], lo[4];
#pragma unroll
  for (int j = 0; j < 4; ++j) {
    hi[j] = f2bf(f[j]);
    lo[j] = f2bf(f[j] - bf2f(hi[j]));
  }
  uint2 uh, ul;
  uh.x = (uint)hi[0] | ((uint)hi[1] << 16); uh.y = (uint)hi[2] | ((uint)hi[3] << 16);
  ul.x = (uint)lo[0] | ((uint)lo[1] << 16); ul.y = (uint)lo[2] | ((uint)lo[3] << 16);
  *(uint2*)&wsu[(size_t)idx4 * 4] = uh;
  *(uint2*)&wsu[W_U16 + (size_t)idx4 * 4] = ul;
}

// ---------------------------------------------------------------------------
// Kernel X: subsample + transpose + split x -> xsT[n][c] hi/lo bf16.
// ---------------------------------------------------------------------------
__global__ __launch_bounds__(256) void prep_x_kernel(
    const float* __restrict__ x, ushort* __restrict__ wsu, int b0) {
  const int hh = blockIdx.x, cc = blockIdx.y, bb = blockIdx.z;
  const int b = b0 + bb;
  const int c0 = cc * 64;
  ushort* slot = wsu + 2 * (size_t)W_U16 + (size_t)bb * SLOT_U16;
  ushort* xthi = slot;
  ushort* xtlo = slot + XT_U16;
  const float* xb = x + ((size_t)b * 384 + c0) * 9216 + 192 * hh;

  __shared__ float T[64][49];
  const int tid = threadIdx.x;
#pragma unroll
  for (int i = 0; i < 8; ++i) {
    int idx = tid + 256 * i;
    int cl = idx >> 5, q = idx & 31;
    if (q < 24) {
      float4 v = *(const float4*)&xb[(size_t)cl * 9216 + 4 * q];
      T[cl][2 * q] = v.x;
      T[cl][2 * q + 1] = v.z;
    }
  }
  __syncthreads();
#pragma unroll
  for (int i = 0; i < 2; ++i) {
    int item = tid + 256 * i;
    if (item < 384) {
      int ww = item >> 3, cg = item & 7;
      int n = hh * 48 + ww;
      uint uh[4], ul[4];
#pragma unroll
      for (int p = 0; p < 4; ++p) {
        float f0 = T[8 * cg + 2 * p][ww], f1 = T[8 * cg + 2 * p + 1][ww];
        ushort h0 = f2bf(f0), h1 = f2bf(f1);
        ushort l0 = f2bf(f0 - bf2f(h0)), l1 = f2bf(f1 - bf2f(h1));
        uh[p] = (uint)h0 | ((uint)h1 << 16);
        ul[p] = (uint)l0 | ((uint)l1 << 16);
      }
      uint4 H = {uh[0], uh[1], uh[2], uh[3]};
      uint4 L = {ul[0], ul[1], ul[2], ul[3]};
      *(uint4*)&xthi[(size_t)n * 384 + c0 + 8 * cg] = H;
      *(uint4*)&xtlo[(size_t)n * 384 + c0 + 8 * cg] = L;
    }
  }
}

// ---------------------------------------------------------------------------
// Kernel G: MFMA projection GEMM with reg-staged prefetch across K-steps.
// Staging uses NAMED uint4 registers (t0..t7) — no arrays/lambdas, so the
// allocator keeps them in VGPRs (round-5 lesson: array+lambda = scratch).
// Epilogue writes attention-ready layouts:
//  t=0 (q): [n][64] hi/lo (already log2e-scaled via W)
//  t=1 (k): per-64-key swizzled tile, planes hi/lo (tile = 24 KB: Khi|Klo|V)
//  t=2 (v): same tile, plane 2, rows = d, cols = key, row-swizzled
// ---------------------------------------------------------------------------
__global__ __launch_bounds__(256) void qkv_mfma_kernel(
    const ushort* __restrict__ wsu, int b0) {
  const int nT = blockIdx.x, oT = blockIdx.y, bb = blockIdx.z;
  const ushort* whi = wsu;
  const ushort* wlo = wsu + W_U16;
  const ushort* slot = wsu + 2 * (size_t)W_U16 + (size_t)bb * SLOT_U16;
  const ushort* xthi = slot;
  const ushort* xtlo = slot + XT_U16;
  const int oBase = oT * 64, nBase = nT * 64;

  __shared__ __align__(16) ushort Wh[64 * 64];
  __shared__ __align__(16) ushort Wl[64 * 64];
  __shared__ __align__(16) ushort Xh[64 * 64];
  __shared__ __align__(16) ushort Xl[64 * 64];

  const int tid = threadIdx.x;
  const int w = tid >> 6, l = tid & 63;
  const int lq = l & 15, lh = l >> 4;

  // Staging geometry: r0 = tid>>3 in [0,32), g = tid&7; rows r0 and r0+32.
  const int r0 = tid >> 3, g0 = tid & 7;
  const size_t srcA = (size_t)(oBase + r0) * 384 + 8 * g0;       // W rows
  const size_t srcB = (size_t)(nBase + r0) * 384 + 8 * g0;       // X rows
  const int dst0 = r0 * 64 + 8 * (g0 ^ (r0 & 7));
  const int dst1 = dst0 + 2048;                                   // row+32

  f32x4 acc[4];
#pragma unroll
  for (int f = 0; f < 4; ++f) acc[f] = (f32x4){0.f, 0.f, 0.f, 0.f};

  uint4 t0, t1, t2, t3, t4, t5, t6, t7;
#define QSTAGE(c0)                                                        \
  {                                                                       \
    t0 = *(const uint4*)&whi[srcA + (c0)];                                \
    t1 = *(const uint4*)&whi[srcA + 32 * 384 + (c0)];                     \
    t2 = *(const uint4*)&wlo[srcA + (c0)];                                \
    t3 = *(const uint4*)&wlo[srcA + 32 * 384 + (c0)];                     \
    t4 = *(const uint4*)&xthi[srcB + (c0)];                               \
    t5 = *(const uint4*)&xthi[srcB + 32 * 384 + (c0)];                    \
    t6 = *(const uint4*)&xtlo[srcB + (c0)];                               \
    t7 = *(const uint4*)&xtlo[srcB + 32 * 384 + (c0)];                    \
  }
#define QCOMMIT()                                                         \
  {                                                                       \
    *(uint4*)&Wh[dst0] = t0; *(uint4*)&Wh[dst1] = t1;                     \
    *(uint4*)&Wl[dst0] = t2; *(uint4*)&Wl[dst1] = t3;                     \
    *(uint4*)&Xh[dst0] = t4; *(uint4*)&Xh[dst1] = t5;                     \
    *(uint4*)&Xl[dst0] = t6; *(uint4*)&Xl[dst1] = t7;                     \
  }

  QSTAGE(0)
  for (int step = 0; step < 6; ++step) {
    QCOMMIT()            // waits vmcnt on t0..t7 sources
    __syncthreads();     // LDS tile ready
    if (step < 5) QSTAGE((step + 1) * 64)  // next loads in flight
    __builtin_amdgcn_s_setprio(1);
#pragma unroll
    for (int s = 0; s < 2; ++s) {
      const int nrow = 16 * w + lq;
      const int g = 4 * s + lh;
      const int noff = nrow * 64 + 8 * (g ^ (nrow & 7));
      bf16x8 xh = *(const bf16x8*)&Xh[noff];
      bf16x8 xl = *(const bf16x8*)&Xl[noff];
#pragma unroll
      for (int f = 0; f < 4; ++f) {
        const int orow = 16 * f + lq;
        const int ooff = orow * 64 + 8 * (g ^ (orow & 7));
        bf16x8 wh_ = *(const bf16x8*)&Wh[ooff];
        bf16x8 wl_ = *(const bf16x8*)&Wl[ooff];
        acc[f] = __builtin_amdgcn_mfma_f32_16x16x32_bf16(wh_, xh, acc[f], 0, 0, 0);
        acc[f] = __builtin_amdgcn_mfma_f32_16x16x32_bf16(wh_, xl, acc[f], 0, 0, 0);
        acc[f] = __builtin_amdgcn_mfma_f32_16x16x32_bf16(wl_, xh, acc[f], 0, 0, 0);
      }
    }
    __builtin_amdgcn_s_setprio(0);
    __syncthreads();     // all waves done reading before next commit
  }

  const int t = oT % 3, head = oT / 3;
  ushort* pb = (ushort*)slot + 2 * (size_t)XT_U16 + (size_t)head * HEAD_U16;
  if (t == 0) {  // q: [n][64] hi/lo (log2e already folded into W)
    ushort* phi = pb;
    ushort* plo = pb + PLANE_U16;
    const int n = nBase + 16 * w + lq;
#pragma unroll
    for (int f = 0; f < 4; ++f) {
      ushort hi[4], lo[4];
#pragma unroll
      for (int r = 0; r < 4; ++r) {
        hi[r] = f2bf(acc[f][r]);
        lo[r] = f2bf(acc[f][r] - bf2f(hi[r]));
      }
      uint2 uh, ul;
      uh.x = (uint)hi[0] | ((uint)hi[1] << 16); uh.y = (uint)hi[2] | ((uint)hi[3] << 16);
      ul.x = (uint)lo[0] | ((uint)lo[1] << 16); ul.y = (uint)lo[2] | ((uint)lo[3] << 16);
      const int d = 16 * f + 4 * lh;
      *(uint2*)&phi[(size_t)n * 64 + d] = uh;
      *(uint2*)&plo[(size_t)n * 64 + d] = ul;
    }
  } else if (t == 1) {  // k: swizzled tile planes 0 (hi) and 1 (lo)
    ushort* kv = pb + 2 * (size_t)PLANE_U16 + (size_t)nT * 12288;
    const int row = 16 * w + lq;  // key within tile
#pragma unroll
    for (int f = 0; f < 4; ++f) {
      ushort hi[4], lo[4];
#pragma unroll
      for (int r = 0; r < 4; ++r) {
        hi[r] = f2bf(acc[f][r]);
        lo[r] = f2bf(acc[f][r] - bf2f(hi[r]));
      }
      uint2 uh, ul;
      uh.x = (uint)hi[0] | ((uint)hi[1] << 16); uh.y = (uint)hi[2] | ((uint)hi[3] << 16);
      ul.x = (uint)lo[0] | ((uint)lo[1] << 16); ul.y = (uint)lo[2] | ((uint)lo[3] << 16);
      const int idx = row * 64 + 8 * ((2 * f + (lh >> 1)) ^ (row & 7)) + 4 * (lh & 1);
      *(uint2*)&kv[idx] = uh;
      *(uint2*)&kv[4096 + idx] = ul;
    }
  } else {  // v: swizzled tile plane 2, rows = d
    ushort* pv = pb + 2 * (size_t)PLANE_U16 + (size_t)nT * 12288 + 8192;
    const int col = 16 * w + lq;  // key within tile
    const int cg = col >> 3, cr = col & 7;
#pragma unroll
    for (int f = 0; f < 4; ++f)
#pragma unroll
      for (int r = 0; r < 4; ++r) {
        const int row = 16 * f + 4 * lh + r;
        pv[row * 64 + 8 * (cg ^ (row & 7)) + cr] = f2bf(acc[f][r]);
      }
  }
}

// ---------------------------------------------------------------------------
// Kernel B: MFMA flash attention.  Reg-staged prefetch of pre-swizzled 24 KB
// KV tiles using NAMED registers s0..s5 (no arrays -> no scratch spill);
// exp2-domain softmax with defer-max; cvt_pk P packing; setprio on MFMA.
// ---------------------------------------------------------------------------
__global__ __launch_bounds__(256, 4) void attn_mfma_kernel(
    const ushort* __restrict__ wsu, float* __restrict__ out, int b0) {
  const int qt = blockIdx.x, h = blockIdx.y, bb = blockIdx.z;
  const int b = b0 + bb;
  const ushort* pb = wsu + 2 * (size_t)W_U16 + (size_t)bb * SLOT_U16 +
                     2 * (size_t)XT_U16 + (size_t)h * HEAD_U16;
  const ushort* qhiP = pb;
  const ushort* qloP = pb + PLANE_U16;
  const char* kvG = (const char*)(pb + 2 * (size_t)PLANE_U16);  // 36 x 24576 B
  const int n0 = qt * 64;

  __shared__ __align__(16) ushort KV[12288];   // Khi | Klo | Vh (pre-swizzled)
  __shared__ __align__(16) ushort Pw[4][16 * 64];

  const int tid = threadIdx.x;
  const int w = tid >> 6;
  const int l = tid & 63;
  const int lq = l & 15;
  const int lh = l >> 4;

  bf16x8 qh[2], ql[2];
  {
    const int qrow = n0 + 16 * w + lq;
    const ushort* qr = qhiP + (size_t)qrow * 64 + 8 * lh;
    const ushort* qr2 = qloP + (size_t)qrow * 64 + 8 * lh;
    qh[0] = *(const bf16x8*)(qr);
    qh[1] = *(const bf16x8*)(qr + 32);
    ql[0] = *(const bf16x8*)(qr2);
    ql[1] = *(const bf16x8*)(qr2 + 32);
  }

  f32x4 oac[4];
#pragma unroll
  for (int i = 0; i < 4; ++i) oac[i] = (f32x4){0.f, 0.f, 0.f, 0.f};
  float m_run = -3.0e38f, l_run = 0.f;

  const char* gbase = kvG + w * 6144 + l * 16;
  char* lbase = (char*)&KV[0] + w * 6144 + l * 16;

  uint4 s0, s1, s2, s3, s4, s5;
#define ASTAGE(mt)                                                        \
  {                                                                       \
    const char* p_ = gbase + (size_t)(mt) * 24576;                        \
    s0 = *(const uint4*)(p_);                                             \
    s1 = *(const uint4*)(p_ + 1024);                                      \
    s2 = *(const uint4*)(p_ + 2048);                                      \
    s3 = *(const uint4*)(p_ + 3072);                                      \
    s4 = *(const uint4*)(p_ + 4096);                                      \
    s5 = *(const uint4*)(p_ + 5120);                                      \
  }
#define ACOMMIT()                                                         \
  {                                                                       \
    *(uint4*)(lbase) = s0;                                                \
    *(uint4*)(lbase + 1024) = s1;                                         \
    *(uint4*)(lbase + 2048) = s2;                                         \
    *(uint4*)(lbase + 3072) = s3;                                         \
    *(uint4*)(lbase + 4096) = s4;                                         \
    *(uint4*)(lbase + 5120) = s5;                                         \
  }

  ASTAGE(0)
  ACOMMIT()
  __syncthreads();

  for (int mt = 0; mt < 36; ++mt) {
    const bool hasNext = (mt + 1 < 36);
    if (hasNext) ASTAGE(mt + 1)  // global loads in flight during compute

    const ushort* Khi = &KV[0];
    const ushort* Klo = &KV[4096];
    const ushort* Vh = &KV[8192];

    f32x4 st[4];
#pragma unroll
    for (int f = 0; f < 4; ++f) st[f] = (f32x4){0.f, 0.f, 0.f, 0.f};
    __builtin_amdgcn_s_setprio(1);
#pragma unroll
    for (int f = 0; f < 4; ++f) {
#pragma unroll
      for (int s = 0; s < 2; ++s) {
        const int row = 16 * f + lq;
        const int g = 4 * s + lh;
        const int off = row * 64 + 8 * (g ^ (row & 7));
        bf16x8 ah = *(const bf16x8*)&Khi[off];
        bf16x8 al = *(const bf16x8*)&Klo[off];
        st[f] = __builtin_amdgcn_mfma_f32_16x16x32_bf16(ah, qh[s], st[f], 0, 0, 0);
        st[f] = __builtin_amdgcn_mfma_f32_16x16x32_bf16(ah, ql[s], st[f], 0, 0, 0);
        st[f] = __builtin_amdgcn_mfma_f32_16x16x32_bf16(al, qh[s], st[f], 0, 0, 0);
      }
    }
    __builtin_amdgcn_s_setprio(0);

    // Row max across this tile (partners at lane^16, lane^32).
    float tm = max3f(st[0][0], st[0][1], st[0][2]);
    tm = max3f(tm, st[0][3], st[1][0]);
    tm = max3f(tm, st[1][1], st[1][2]);
    tm = max3f(tm, st[1][3], st[2][0]);
    tm = max3f(tm, st[2][1], st[2][2]);
    tm = max3f(tm, st[2][3], st[3][0]);
    tm = max3f(tm, st[3][1], st[3][2]);
    tm = fmaxf(tm, st[3][3]);
    tm = fmaxf(tm, __shfl_xor(tm, 16));
    tm = fmaxf(tm, __shfl_xor(tm, 32));

    // Defer-max: only rescale when the running max grew by > 8 (exp2 domain).
    if (__any(tm > m_run + 8.0f)) {
      const float mnew = fmaxf(m_run, tm);
      const float sc = exp2_fast(m_run - mnew);
#pragma unroll
      for (int fd = 0; fd < 4; ++fd) oac[fd] *= sc;
      l_run *= sc;
      m_run = mnew;
    }

    float ls = 0.f;
#pragma unroll
    for (int f = 0; f < 4; ++f)
#pragma unroll
      for (int r = 0; r < 4; ++r) {
        st[f][r] = exp2_fast(st[f][r] - m_run);
        ls += st[f][r];
      }
    ls += __shfl_xor(ls, 16);
    ls += __shfl_xor(ls, 32);
    l_run += ls;

    // Pack P to bf16 and bounce through per-wave swizzled LDS.
    ushort* pw = &Pw[w][0];
#pragma unroll
    for (int f = 0; f < 4; ++f) {
      uint2 uu;
      uu.x = cvt_pk_bf16(st[f][0], st[f][1]);
      uu.y = cvt_pk_bf16(st[f][2], st[f][3]);
      int ui = lq * 64 + 8 * ((2 * f + (lh >> 1)) ^ (lq & 7)) + 4 * (lh & 1);
      *(uint2*)&pw[ui] = uu;
    }
    bf16x8 pbf[2];
#pragma unroll
    for (int s = 0; s < 2; ++s)
      pbf[s] = *(const bf16x8*)&pw[lq * 64 + 8 * ((4 * s + lh) ^ (lq & 7))];

    __builtin_amdgcn_s_setprio(1);
#pragma unroll
    for (int fd = 0; fd < 4; ++fd) {
#pragma unroll
      for (int s = 0; s < 2; ++s) {
        const int row = 16 * fd + lq;
        const int g = 4 * s + lh;
        bf16x8 av = *(const bf16x8*)&Vh[row * 64 + 8 * (g ^ (row & 7))];
        oac[fd] = __builtin_amdgcn_mfma_f32_16x16x32_bf16(av, pbf[s], oac[fd], 0, 0, 0);
      }
    }
    __builtin_amdgcn_s_setprio(0);

    if (hasNext) {
      __syncthreads();   // all waves done reading KV
      ACOMMIT()          // vmcnt wait on s0..s5 sources is free by now
      __syncthreads();   // next tile ready
    }
  }

  const float inv = 1.f / l_run;
  const int ncol = n0 + 16 * w + lq;
#pragma unroll
  for (int fd = 0; fd < 4; ++fd)
#pragma unroll
    for (int r = 0; r < 4; ++r)
      out[((size_t)b * 384 + h * 64 + 16 * fd + 4 * lh + r) * NTOK + ncol] =
          oac[fd][r] * inv;
}

extern "C" void kernel_launch(void* const* d_in, const int* in_sizes, int n_in,
                              void* d_out, int out_size, void* d_ws,
                              size_t ws_size, hipStream_t stream) {
  const float* x = (const float*)d_in[0];
  const float* w = (const float*)d_in[1];
  float* out = (float*)d_out;
  ushort* wsu = (ushort*)d_ws;

  int nbFit = (int)((ws_size - WBYTES) / SLOT_BYTES);
  if (nbFit < 1) nbFit = 1;
  if (nbFit > NB) nbFit = NB;

  hipLaunchKernelGGL(prep_w_kernel, dim3(432), dim3(256), 0, stream, w, wsu);
  for (int b0 = 0; b0 < NB; b0 += nbFit) {
    int nb = NB - b0;
    if (nb > nbFit) nb = nbFit;
    hipLaunchKernelGGL(prep_x_kernel, dim3(48, 6, nb), dim3(256), 0, stream,
                       x, wsu, b0);
    hipLaunchKernelGGL(qkv_mfma_kernel, dim3(36, 18, nb), dim3(256), 0, stream,
                       wsu, b0);
    hipLaunchKernelGGL(attn_mfma_kernel, dim3(36, 6, nb), dim3(256), 0, stream,
                       wsu, out, b0);
  }
}

// Round 7
// 193.351 us; speedup vs baseline: 3.6781x; 1.2442x over previous
//
#include <hip/hip_runtime.h>

// B=8, C=384, 96x96 stride-2 -> 48x48, N=2304 tokens.
// qkv = W(1152x384) @ xs(384xN); 6 heads x (q,k,v) of 64 dims.
// attn = softmax(q^T k); out[d][n] = sum_m v[d][m] P[n][m].
// All matmuls on fp16 MFMA, 2-term split: exact side = hi+lo fp16 pair,
// other side single fp16 (error ~2^-11).  W pre-scaled by 1024 to keep
// W_lo out of fp16 denormals; q rows also carry log2(e) (exp2 softmax).

#define NTOK 2304
#define NB 8
#define W_U16 (1152 * 384)             // one W fp16 plane
#define XT_U16 (NTOK * 384)            // xsT fp16 plane (single)
#define PLANE_U16 (NTOK * 64)          // one qkv fp16 plane (147456)
#define KVTILE_U16 8192                // Kh(4096) + V(4096) per 64-key tile
#define HEAD_U16 (2 * PLANE_U16 + 36 * KVTILE_U16)   // Qh,Ql + 36 KV tiles
#define SLOT_U16 (XT_U16 + 6 * HEAD_U16)
#define SLOT_BYTES ((size_t)SLOT_U16 * 2)   // 8.85 MB / batch
#define WBYTES ((size_t)W_U16 * 2 * 2)      // Wh+Wl = 1.77 MB
#define LOG2E 1.4426950408889634f
#define WSCALE 1024.0f
#define WS_INV (1.0f / 1024.0f)

typedef __attribute__((ext_vector_type(8))) _Float16 f16x8;
typedef __attribute__((ext_vector_type(4))) float f32x4;

__device__ __forceinline__ ushort f2h(float f) {
  union { _Float16 h; ushort u; } v; v.h = (_Float16)f; return v.u;
}
__device__ __forceinline__ float h2f(ushort u) {
  union { ushort u; _Float16 h; } v; v.u = u; return (float)v.h;
}
__device__ __forceinline__ uint cvt_pk_f16(float lo, float hi) {
  uint r;
  asm("v_cvt_pkrtz_f16_f32 %0, %1, %2" : "=v"(r) : "v"(lo), "v"(hi));
  return r;
}
__device__ __forceinline__ float exp2_fast(float x) {
  float r;
  asm("v_exp_f32 %0, %1" : "=v"(r) : "v"(x));
  return r;
}
__device__ __forceinline__ float max3f(float a, float b, float c) {
  float r;
  asm("v_max3_f32 %0, %1, %2, %3" : "=v"(r) : "v"(a), "v"(b), "v"(c));
  return r;
}

// ---------------------------------------------------------------------------
// Kernel W: split 1024*W into hi/lo fp16 planes; q-rows also carry log2(e).
// ---------------------------------------------------------------------------
__global__ __launch_bounds__(256) void prep_w_kernel(
    const float* __restrict__ w, ushort* __restrict__ wsu) {
  const int idx4 = blockIdx.x * 256 + threadIdx.x;  // 110592 total
  const int o = idx4 / 96;                          // W row
  const float scale = (((o % 192) < 64) ? LOG2E : 1.0f) * WSCALE;
  float4 v = *(const float4*)&w[(size_t)idx4 * 4];
  float f[4] = {v.x * scale, v.y * scale, v.z * scale, v.w * scale};
  ushort hi[4], lo[4];
#pragma unroll
  for (int j = 0; j < 4; ++j) {
    hi[j] = f2h(f[j]);
    lo[j] = f2h(f[j] - h2f(hi[j]));
  }
  uint2 uh, ul;
  uh.x = (uint)hi[0] | ((uint)hi[1] << 16); uh.y = (uint)hi[2] | ((uint)hi[3] << 16);
  ul.x = (uint)lo[0] | ((uint)lo[1] << 16); ul.y = (uint)lo[2] | ((uint)lo[3] << 16);
  *(uint2*)&wsu[(size_t)idx4 * 4] = uh;
  *(uint2*)&wsu[W_U16 + (size_t)idx4 * 4] = ul;
}

// ---------------------------------------------------------------------------
// Kernel X: subsample + transpose x -> xsT[n][c] single fp16 plane.
// ---------------------------------------------------------------------------
__global__ __launch_bounds__(256) void prep_x_kernel(
    const float* __restrict__ x, ushort* __restrict__ wsu, int b0) {
  const int hh = blockIdx.x, cc = blockIdx.y, bb = blockIdx.z;
  const int b = b0 + bb;
  const int c0 = cc * 64;
  ushort* xth = wsu + 2 * (size_t)W_U16 + (size_t)bb * SLOT_U16;
  const float* xb = x + ((size_t)b * 384 + c0) * 9216 + 192 * hh;

  __shared__ float T[64][49];
  const int tid = threadIdx.x;
#pragma unroll
  for (int i = 0; i < 8; ++i) {
    int idx = tid + 256 * i;
    int cl = idx >> 5, q = idx & 31;
    if (q < 24) {
      float4 v = *(const float4*)&xb[(size_t)cl * 9216 + 4 * q];
      T[cl][2 * q] = v.x;
      T[cl][2 * q + 1] = v.z;
    }
  }
  __syncthreads();
#pragma unroll
  for (int i = 0; i < 2; ++i) {
    int item = tid + 256 * i;
    if (item < 384) {
      int ww = item >> 3, cg = item & 7;
      int n = hh * 48 + ww;
      uint uh[4];
#pragma unroll
      for (int p = 0; p < 4; ++p) {
        float f0 = T[8 * cg + 2 * p][ww], f1 = T[8 * cg + 2 * p + 1][ww];
        uh[p] = (uint)f2h(f0) | ((uint)f2h(f1) << 16);
      }
      uint4 H = {uh[0], uh[1], uh[2], uh[3]};
      *(uint4*)&xth[(size_t)n * 384 + c0 + 8 * cg] = H;
    }
  }
}

// ---------------------------------------------------------------------------
// Kernel G: fp16 MFMA projection GEMM, 2-term (Wh+Wl)*Xh, reg-prefetch.
// Epilogue (acc * 1/1024) writes attention-ready layouts:
//  t=0 (q): [n][64] fp16 hi/lo planes
//  t=1 (k): swizzled [key][d] fp16 in KV tile plane 0
//  t=2 (v): swizzled [d][key] fp16 in KV tile plane 1
// ---------------------------------------------------------------------------
__global__ __launch_bounds__(256) void qkv_mfma_kernel(
    const ushort* __restrict__ wsu, int b0) {
  const int nT = blockIdx.x, oT = blockIdx.y, bb = blockIdx.z;
  const ushort* whi = wsu;
  const ushort* wlo = wsu + W_U16;
  const ushort* slot = wsu + 2 * (size_t)W_U16 + (size_t)bb * SLOT_U16;
  const ushort* xth = slot;
  const int oBase = oT * 64, nBase = nT * 64;

  __shared__ __align__(16) ushort Wh[64 * 64];
  __shared__ __align__(16) ushort Wl[64 * 64];
  __shared__ __align__(16) ushort Xh[64 * 64];

  const int tid = threadIdx.x;
  const int w = tid >> 6, l = tid & 63;
  const int lq = l & 15, lh = l >> 4;

  const int r0 = tid >> 3, g0 = tid & 7;
  const size_t srcA = (size_t)(oBase + r0) * 384 + 8 * g0;   // W rows
  const size_t srcB = (size_t)(nBase + r0) * 384 + 8 * g0;   // X rows
  const int dst0 = r0 * 64 + 8 * (g0 ^ (r0 & 7));
  const int dst1 = dst0 + 2048;                               // row+32

  f32x4 acc[4];
#pragma unroll
  for (int f = 0; f < 4; ++f) acc[f] = (f32x4){0.f, 0.f, 0.f, 0.f};

  uint4 t0, t1, t2, t3, t4, t5;
#define QSTAGE(c0)                                                        \
  {                                                                       \
    t0 = *(const uint4*)&whi[srcA + (c0)];                                \
    t1 = *(const uint4*)&whi[srcA + 32 * 384 + (c0)];                     \
    t2 = *(const uint4*)&wlo[srcA + (c0)];                                \
    t3 = *(const uint4*)&wlo[srcA + 32 * 384 + (c0)];                     \
    t4 = *(const uint4*)&xth[srcB + (c0)];                                \
    t5 = *(const uint4*)&xth[srcB + 32 * 384 + (c0)];                     \
  }
#define QCOMMIT()                                                         \
  {                                                                       \
    *(uint4*)&Wh[dst0] = t0; *(uint4*)&Wh[dst1] = t1;                     \
    *(uint4*)&Wl[dst0] = t2; *(uint4*)&Wl[dst1] = t3;                     \
    *(uint4*)&Xh[dst0] = t4; *(uint4*)&Xh[dst1] = t5;                     \
  }

  QSTAGE(0)
  for (int step = 0; step < 6; ++step) {
    QCOMMIT()
    __syncthreads();
    if (step < 5) QSTAGE((step + 1) * 64)
    __builtin_amdgcn_s_setprio(1);
#pragma unroll
    for (int s = 0; s < 2; ++s) {
      const int nrow = 16 * w + lq;
      const int g = 4 * s + lh;
      const int noff = nrow * 64 + 8 * (g ^ (nrow & 7));
      f16x8 xh = *(const f16x8*)&Xh[noff];
#pragma unroll
      for (int f = 0; f < 4; ++f) {
        const int orow = 16 * f + lq;
        const int ooff = orow * 64 + 8 * (g ^ (orow & 7));
        f16x8 wh_ = *(const f16x8*)&Wh[ooff];
        f16x8 wl_ = *(const f16x8*)&Wl[ooff];
        acc[f] = __builtin_amdgcn_mfma_f32_16x16x32_f16(wh_, xh, acc[f], 0, 0, 0);
        acc[f] = __builtin_amdgcn_mfma_f32_16x16x32_f16(wl_, xh, acc[f], 0, 0, 0);
      }
    }
    __builtin_amdgcn_s_setprio(0);
    __syncthreads();
  }

  const int t = oT % 3, head = oT / 3;
  ushort* pb = (ushort*)slot + (size_t)XT_U16 + (size_t)head * HEAD_U16;
  if (t == 0) {  // q: [n][64] fp16 hi/lo (log2e folded via W)
    ushort* phi = pb;
    ushort* plo = pb + PLANE_U16;
    const int n = nBase + 16 * w + lq;
#pragma unroll
    for (int f = 0; f < 4; ++f) {
      ushort hi[4], lo[4];
#pragma unroll
      for (int r = 0; r < 4; ++r) {
        const float v = acc[f][r] * WS_INV;
        hi[r] = f2h(v);
        lo[r] = f2h(v - h2f(hi[r]));
      }
      uint2 uh, ul;
      uh.x = (uint)hi[0] | ((uint)hi[1] << 16); uh.y = (uint)hi[2] | ((uint)hi[3] << 16);
      ul.x = (uint)lo[0] | ((uint)lo[1] << 16); ul.y = (uint)lo[2] | ((uint)lo[3] << 16);
      const int d = 16 * f + 4 * lh;
      *(uint2*)&phi[(size_t)n * 64 + d] = uh;
      *(uint2*)&plo[(size_t)n * 64 + d] = ul;
    }
  } else if (t == 1) {  // k: swizzled [key][d] fp16, KV tile plane 0
    ushort* kv = pb + 2 * (size_t)PLANE_U16 + (size_t)nT * KVTILE_U16;
    const int row = 16 * w + lq;  // key within tile
#pragma unroll
    for (int f = 0; f < 4; ++f) {
      ushort hv[4];
#pragma unroll
      for (int r = 0; r < 4; ++r) hv[r] = f2h(acc[f][r] * WS_INV);
      uint2 uh;
      uh.x = (uint)hv[0] | ((uint)hv[1] << 16); uh.y = (uint)hv[2] | ((uint)hv[3] << 16);
      const int idx = row * 64 + 8 * ((2 * f + (lh >> 1)) ^ (row & 7)) + 4 * (lh & 1);
      *(uint2*)&kv[idx] = uh;
    }
  } else {  // v: swizzled [d][key] fp16, KV tile plane 1
    ushort* pv = pb + 2 * (size_t)PLANE_U16 + (size_t)nT * KVTILE_U16 + 4096;
    const int col = 16 * w + lq;  // key within tile
    const int cg = col >> 3, cr = col & 7;
#pragma unroll
    for (int f = 0; f < 4; ++f)
#pragma unroll
      for (int r = 0; r < 4; ++r) {
        const int row = 16 * f + 4 * lh + r;
        pv[row * 64 + 8 * (cg ^ (row & 7)) + cr] = f2h(acc[f][r] * WS_INV);
      }
  }
}

// ---------------------------------------------------------------------------
// Kernel B: fp16 MFMA flash attention.  16 KB pre-swizzled KV tiles,
// reg-staged prefetch (named s0..s3), S = Kh*(Qh+Ql), exp2 softmax with
// defer-max, pkrtz P packing, setprio around MFMA clusters.
// ---------------------------------------------------------------------------
__global__ __launch_bounds__(256, 5) void attn_mfma_kernel(
    const ushort* __restrict__ wsu, float* __restrict__ out, int b0) {
  const int qt = blockIdx.x, h = blockIdx.y, bb = blockIdx.z;
  const int b = b0 + bb;
  const ushort* pb = wsu + 2 * (size_t)W_U16 + (size_t)bb * SLOT_U16 +
                     (size_t)XT_U16 + (size_t)h * HEAD_U16;
  const ushort* qhP = pb;
  const ushort* qlP = pb + PLANE_U16;
  const char* kvG = (const char*)(pb + 2 * (size_t)PLANE_U16);  // 36 x 16384 B
  const int n0 = qt * 64;

  __shared__ __align__(16) ushort KV[8192];    // Kh | Vh (pre-swizzled)
  __shared__ __align__(16) ushort Pw[4][16 * 64];

  const int tid = threadIdx.x;
  const int w = tid >> 6;
  const int l = tid & 63;
  const int lq = l & 15;
  const int lh = l >> 4;

  f16x8 qh[2], ql[2];
  {
    const int qrow = n0 + 16 * w + lq;
    const ushort* qr = qhP + (size_t)qrow * 64 + 8 * lh;
    const ushort* qr2 = qlP + (size_t)qrow * 64 + 8 * lh;
    qh[0] = *(const f16x8*)(qr);
    qh[1] = *(const f16x8*)(qr + 32);
    ql[0] = *(const f16x8*)(qr2);
    ql[1] = *(const f16x8*)(qr2 + 32);
  }

  f32x4 oac[4];
#pragma unroll
  for (int i = 0; i < 4; ++i) oac[i] = (f32x4){0.f, 0.f, 0.f, 0.f};
  float m_run = -3.0e38f, l_run = 0.f;

  const char* gbase = kvG + w * 4096 + l * 16;
  char* lbase = (char*)&KV[0] + w * 4096 + l * 16;

  uint4 s0, s1, s2, s3;
#define ASTAGE(mt)                                                        \
  {                                                                       \
    const char* p_ = gbase + (size_t)(mt) * 16384;                        \
    s0 = *(const uint4*)(p_);                                             \
    s1 = *(const uint4*)(p_ + 1024);                                      \
    s2 = *(const uint4*)(p_ + 2048);                                      \
    s3 = *(const uint4*)(p_ + 3072);                                      \
  }
#define ACOMMIT()                                                         \
  {                                                                       \
    *(uint4*)(lbase) = s0;                                                \
    *(uint4*)(lbase + 1024) = s1;                                         \
    *(uint4*)(lbase + 2048) = s2;                                         \
    *(uint4*)(lbase + 3072) = s3;                                         \
  }

  ASTAGE(0)
  ACOMMIT()
  __syncthreads();

  for (int mt = 0; mt < 36; ++mt) {
    const bool hasNext = (mt + 1 < 36);
    if (hasNext) ASTAGE(mt + 1)  // global loads in flight during compute

    const ushort* Kh = &KV[0];
    const ushort* Vh = &KV[4096];

    f32x4 st[4];
#pragma unroll
    for (int f = 0; f < 4; ++f) st[f] = (f32x4){0.f, 0.f, 0.f, 0.f};
    __builtin_amdgcn_s_setprio(1);
#pragma unroll
    for (int f = 0; f < 4; ++f) {
#pragma unroll
      for (int s = 0; s < 2; ++s) {
        const int row = 16 * f + lq;
        const int g = 4 * s + lh;
        const int off = row * 64 + 8 * (g ^ (row & 7));
        f16x8 kh = *(const f16x8*)&Kh[off];
        st[f] = __builtin_amdgcn_mfma_f32_16x16x32_f16(kh, qh[s], st[f], 0, 0, 0);
        st[f] = __builtin_amdgcn_mfma_f32_16x16x32_f16(kh, ql[s], st[f], 0, 0, 0);
      }
    }
    __builtin_amdgcn_s_setprio(0);

    // Row max across this tile (partners at lane^16, lane^32).
    float tm = max3f(st[0][0], st[0][1], st[0][2]);
    tm = max3f(tm, st[0][3], st[1][0]);
    tm = max3f(tm, st[1][1], st[1][2]);
    tm = max3f(tm, st[1][3], st[2][0]);
    tm = max3f(tm, st[2][1], st[2][2]);
    tm = max3f(tm, st[2][3], st[3][0]);
    tm = max3f(tm, st[3][1], st[3][2]);
    tm = fmaxf(tm, st[3][3]);
    tm = fmaxf(tm, __shfl_xor(tm, 16));
    tm = fmaxf(tm, __shfl_xor(tm, 32));

    // Defer-max: only rescale when the running max grew by > 8 (exp2 domain).
    if (__any(tm > m_run + 8.0f)) {
      const float mnew = fmaxf(m_run, tm);
      const float sc = exp2_fast(m_run - mnew);
#pragma unroll
      for (int fd = 0; fd < 4; ++fd) oac[fd] *= sc;
      l_run *= sc;
      m_run = mnew;
    }

    float ls = 0.f;
#pragma unroll
    for (int f = 0; f < 4; ++f)
#pragma unroll
      for (int r = 0; r < 4; ++r) {
        st[f][r] = exp2_fast(st[f][r] - m_run);
        ls += st[f][r];
      }
    ls += __shfl_xor(ls, 16);
    ls += __shfl_xor(ls, 32);
    l_run += ls;

    // Pack P to fp16 and bounce through per-wave swizzled LDS.
    ushort* pw = &Pw[w][0];
#pragma unroll
    for (int f = 0; f < 4; ++f) {
      uint2 uu;
      uu.x = cvt_pk_f16(st[f][0], st[f][1]);
      uu.y = cvt_pk_f16(st[f][2], st[f][3]);
      int ui = lq * 64 + 8 * ((2 * f + (lh >> 1)) ^ (lq & 7)) + 4 * (lh & 1);
      *(uint2*)&pw[ui] = uu;
    }
    f16x8 pbf[2];
#pragma unroll
    for (int s = 0; s < 2; ++s)
      pbf[s] = *(const f16x8*)&pw[lq * 64 + 8 * ((4 * s + lh) ^ (lq & 7))];

    __builtin_amdgcn_s_setprio(1);
#pragma unroll
    for (int fd = 0; fd < 4; ++fd) {
#pragma unroll
      for (int s = 0; s < 2; ++s) {
        const int row = 16 * fd + lq;
        const int g = 4 * s + lh;
        f16x8 av = *(const f16x8*)&Vh[row * 64 + 8 * (g ^ (row & 7))];
        oac[fd] = __builtin_amdgcn_mfma_f32_16x16x32_f16(av, pbf[s], oac[fd], 0, 0, 0);
      }
    }
    __builtin_amdgcn_s_setprio(0);

    if (hasNext) {
      __syncthreads();   // all waves done reading KV
      ACOMMIT()          // vmcnt wait on s0..s3 sources is free by now
      __syncthreads();   // next tile ready
    }
  }

  const float inv = 1.f / l_run;
  const int ncol = n0 + 16 * w + lq;
#pragma unroll
  for (int fd = 0; fd < 4; ++fd)
#pragma unroll
    for (int r = 0; r < 4; ++r)
      out[((size_t)b * 384 + h * 64 + 16 * fd + 4 * lh + r) * NTOK + ncol] =
          oac[fd][r] * inv;
}

extern "C" void kernel_launch(void* const* d_in, const int* in_sizes, int n_in,
                              void* d_out, int out_size, void* d_ws,
                              size_t ws_size, hipStream_t stream) {
  const float* x = (const float*)d_in[0];
  const float* w = (const float*)d_in[1];
  float* out = (float*)d_out;
  ushort* wsu = (ushort*)d_ws;

  int nbFit = (int)((ws_size - WBYTES) / SLOT_BYTES);
  if (nbFit < 1) nbFit = 1;
  if (nbFit > NB) nbFit = NB;

  hipLaunchKernelGGL(prep_w_kernel, dim3(432), dim3(256), 0, stream, w, wsu);
  for (int b0 = 0; b0 < NB; b0 += nbFit) {
    int nb = NB - b0;
    if (nb > nbFit) nb = nbFit;
    hipLaunchKernelGGL(prep_x_kernel, dim3(48, 6, nb), dim3(256), 0, stream,
                       x, wsu, b0);
    hipLaunchKernelGGL(qkv_mfma_kernel, dim3(36, 18, nb), dim3(256), 0, stream,
                       wsu, b0);
    hipLaunchKernelGGL(attn_mfma_kernel, dim3(36, 6, nb), dim3(256), 0, stream,
                       wsu, out, b0);
  }
}